// Round 1
// baseline (23.040 us; speedup 1.0000x reference)
//
#include <hip/hip_runtime.h>
#include <stdint.h>

// Problem constants (from reference setup_inputs)
enum { B_ = 32, K_ = 16, N_ = 256 };

// ws layout (byteified inputs):
//   [0, 65536)              tbl8  : uint8 GF mul table
//   [65536, 73728)          s8    : uint8 s (B*N)
//   [73728, 73728+1048576)  p8    : uint8 P (K*N*N)
#define WS_TBL_OFF 0
#define WS_S_OFF   65536
#define WS_P_OFF   73728
#define WS_NEED    (73728 + 1048576)

__device__ __forceinline__ uint32_t pack4i(int4 v) {
    return (uint32_t)(v.x & 255) | ((uint32_t)(v.y & 255) << 8) |
           ((uint32_t)(v.z & 255) << 16) | ((uint32_t)(v.w & 255) << 24);
}

// ---------------- prep: byteify table/s/P into ws, zero out accumulators ---
// One thread per packed 4-byte word. Word counts: table 16384, s 2048, P 262144.
__global__ __launch_bounds__(256) void prep_full(const int* __restrict__ table,
                                                 const int* __restrict__ s,
                                                 const int* __restrict__ P,
                                                 uint8_t* __restrict__ ws,
                                                 int* __restrict__ out) {
    int tid = blockIdx.x * blockDim.x + threadIdx.x;
    if (blockIdx.x == 0 && threadIdx.x < B_) out[threadIdx.x] = 0;

    uint32_t* tbl8w = (uint32_t*)(ws + WS_TBL_OFF);
    uint32_t* s8w   = (uint32_t*)(ws + WS_S_OFF);
    uint32_t* p8w   = (uint32_t*)(ws + WS_P_OFF);

    if (tid < 16384) {
        int4 v = ((const int4*)table)[tid];
        tbl8w[tid] = pack4i(v);
    } else if (tid < 16384 + 2048) {
        int t = tid - 16384;
        int4 v = ((const int4*)s)[t];
        s8w[t] = pack4i(v);
    } else if (tid < 16384 + 2048 + 262144) {
        int t = tid - (16384 + 2048);
        int4 v = ((const int4*)P)[t];
        p8w[t] = pack4i(v);
    }
}

// Fallback prep: just zero the accumulators.
__global__ void prep_zero(int* __restrict__ out) {
    if (threadIdx.x < B_) out[threadIdx.x] = 0;
}

// ---------------- main kernel ---------------------------------------------
// grid = B*K blocks (b = blockIdx>>4, k = blockIdx&15), 256 threads.
// Thread n computes stP[b,k,n] = XOR_j tbl[s[b,j]][P[k,n,j]] via LDS table,
// then w = tbl[stP][s[b,n]], block-XOR-reduce, atomicAdd(out[b], w_red - m[b,k]).

// 4 lookups from one word of s-bytes (sw) and one word of p-bytes (pw).
#define LK(sw, pw)                                                  \
    v ^= tbl[(((sw) & 255u) << 8) | ((pw) & 255u)];                 \
    v ^= tbl[((sw) & 0xFF00u) | (((pw) >> 8) & 255u)];              \
    v ^= tbl[(((sw) >> 8) & 0xFF00u) | (((pw) >> 16) & 255u)];      \
    v ^= tbl[(((sw) >> 16) & 0xFF00u) | ((pw) >> 24)];

template <int USE_WS>
__global__ __launch_bounds__(256) void gf_main(const int* __restrict__ m,
                                               const int* __restrict__ s32,
                                               const int* __restrict__ P32,
                                               const int* __restrict__ t32,
                                               const uint8_t* __restrict__ ws,
                                               int* __restrict__ out) {
    __shared__ uint8_t tbl[65536];
    __shared__ uint8_t sb[256];
    __shared__ uint32_t wred[4];

    const int b = blockIdx.x >> 4;
    const int k = blockIdx.x & 15;
    const int tid = threadIdx.x;

    if (USE_WS) {
        const uint4* src = (const uint4*)(ws + WS_TBL_OFF);
        uint4* dst = (uint4*)tbl;
#pragma unroll
        for (int i = 0; i < 16; ++i) dst[tid + 256 * i] = src[tid + 256 * i];
        if (tid < 64)
            ((uint32_t*)sb)[tid] = ((const uint32_t*)(ws + WS_S_OFF))[b * 64 + tid];
    } else {
        for (int i = tid; i < 16384; i += 256) {
            int4 v = ((const int4*)t32)[i];
            ((uint32_t*)tbl)[i] = pack4i(v);
        }
        if (tid < 64) {
            int4 v = ((const int4*)s32)[b * 64 + tid];
            ((uint32_t*)sb)[tid] = pack4i(v);
        }
    }
    __syncthreads();

    const int n = tid;
    uint32_t v = 0;
    const uint32_t* sw32 = (const uint32_t*)sb;

    if (USE_WS) {
        const uint8_t* prow = ws + WS_P_OFF + (((size_t)k * N_ + n) << 8);
#pragma unroll
        for (int j0 = 0; j0 < 64; j0 += 4) {  // j0 counts 4-byte words of the row
            uint4 pv = *(const uint4*)(prow + j0 * 4);
            uint32_t w0 = sw32[j0], w1 = sw32[j0 + 1], w2 = sw32[j0 + 2], w3 = sw32[j0 + 3];
            LK(w0, pv.x);
            LK(w1, pv.y);
            LK(w2, pv.z);
            LK(w3, pv.w);
        }
    } else {
        const int4* prow32 = (const int4*)(P32 + ((size_t)k * N_ + n) * N_);
#pragma unroll 4
        for (int j0 = 0; j0 < 64; j0 += 4) {
            uint32_t p0 = pack4i(prow32[j0]);
            uint32_t p1 = pack4i(prow32[j0 + 1]);
            uint32_t p2 = pack4i(prow32[j0 + 2]);
            uint32_t p3 = pack4i(prow32[j0 + 3]);
            uint32_t w0 = sw32[j0], w1 = sw32[j0 + 1], w2 = sw32[j0 + 2], w3 = sw32[j0 + 3];
            LK(w0, p0);
            LK(w1, p1);
            LK(w2, p2);
            LK(w3, p3);
        }
    }

    // second stage: w = tbl[v][s[b,n]]
    uint32_t w = tbl[(v << 8) | (uint32_t)sb[n]];

    // block XOR-reduce (4 waves of 64)
#pragma unroll
    for (int off = 1; off < 64; off <<= 1) w ^= __shfl_xor(w, off, 64);
    const int wave = tid >> 6;
    if ((tid & 63) == 0) wred[wave] = w;
    __syncthreads();
    if (tid == 0) {
        uint32_t x = wred[0] ^ wred[1] ^ wred[2] ^ wred[3];
        int mc = (int)x - m[b * K_ + k];
        atomicAdd(&out[b], mc);
    }
}

// ---------------- finish: out[b] = max(1 - acc[b], 0) ---------------------
__global__ void gf_finish(int* __restrict__ out) {
    if (threadIdx.x < B_) {
        int v = out[threadIdx.x];
        out[threadIdx.x] = max(1 - v, 0);
    }
}

extern "C" void kernel_launch(void* const* d_in, const int* in_sizes, int n_in,
                              void* d_out, int out_size, void* d_ws, size_t ws_size,
                              hipStream_t stream) {
    const int* m     = (const int*)d_in[0];
    const int* s     = (const int*)d_in[1];
    const int* P     = (const int*)d_in[2];
    const int* table = (const int*)d_in[3];
    int* out = (int*)d_out;

    const bool use_ws = (ws_size >= (size_t)WS_NEED);

    if (use_ws) {
        uint8_t* ws = (uint8_t*)d_ws;
        // words total: 16384 + 2048 + 262144 = 280576 -> 1096 blocks of 256
        prep_full<<<1096, 256, 0, stream>>>(table, s, P, ws, out);
        gf_main<1><<<B_ * K_, 256, 0, stream>>>(m, s, P, table, ws, out);
    } else {
        prep_zero<<<1, 64, 0, stream>>>(out);
        gf_main<0><<<B_ * K_, 256, 0, stream>>>(m, s, P, table, nullptr, out);
    }
    gf_finish<<<1, 64, 0, stream>>>(out);
}